// Round 7
// baseline (531.550 us; speedup 1.0000x reference)
//
#include <hip/hip_runtime.h>
#include <math.h>

#define NUM_USERS 100000
#define NUM_ITEMS 50000
#define N_NODES   150000   // NUM_USERS + NUM_ITEMS
#define LATENT    64
#define N_EDGES   2400000
#define BATCH     16384

#define CHUNK 4096
#define NBLK  ((N_EDGES + CHUNK - 1) / CHUNK)   // 586
#define NBKT  ((N_NODES + 511) / 512)           // 293

typedef __attribute__((ext_vector_type(2))) float floatx2;

// fp8 e4m3 pack/unpack via gfx950 HW converters (encode+decode self-consistent)
__device__ __forceinline__ unsigned pk4_fp8(float a, float b, float c, float d) {
    int u = __builtin_amdgcn_cvt_pk_fp8_f32(a, b, 0, false);
    u     = __builtin_amdgcn_cvt_pk_fp8_f32(c, d, u, true);
    return (unsigned)u;
}

// ---------------------------------------------------------------------------
// Inclusive wave-hierarchical scan across NT threads (3 barriers).
// wsums = LDS scratch of NT/64 ints. Entry barrier protects prior wsums use.
// ---------------------------------------------------------------------------
template<int NT>
__device__ __forceinline__ int scan_incl(int v, int tid, int* wsums) {
    int lane = tid & 63, wid = tid >> 6;
    __syncthreads();
    int x = v;
    #pragma unroll
    for (int d = 1; d < 64; d <<= 1) {
        int y = __shfl_up(x, d);
        if (lane >= d) x += y;
    }
    if (lane == 63) wsums[wid] = x;
    __syncthreads();
    constexpr int NW = NT / 64;
    if (wid == 0) {
        int w = (lane < NW) ? wsums[lane] : 0;
        #pragma unroll
        for (int d = 1; d < NW; d <<= 1) {
            int y = __shfl_up(w, d);
            if (lane >= d) w += y;
        }
        if (lane < NW) wsums[lane] = w;
    }
    __syncthreads();
    return x + (wid ? wsums[wid - 1] : 0);
}

// ---------------------------------------------------------------------------
// Fused prep: [blocks 0..NBLK-1]   row histogram via GLOBAL atomics (counts
//                                  pre-zeroed by hipMemsetAsync)
//             [blocks NBLK.. ]     tab = fp8(concat(user_emb, item_emb))
// Random rows over 150K counters: ~16 hits/counter, no hot spot; device-
// scope atomicAdd (G12/m20). Replaces the whole multisplit p1a/p1b stage.
// ---------------------------------------------------------------------------
#define CONCAT_BLKS ((N_NODES * 16) / 256)      // 9375
__global__ __launch_bounds__(256) void k_prep(const float4* __restrict__ ue4,
                                              const float4* __restrict__ ie4,
                                              unsigned* __restrict__ tab,
                                              const int* __restrict__ rows,
                                              int* __restrict__ counts) {
    if (blockIdx.x < NBLK) {
        int e0 = blockIdx.x * CHUNK;
        int cnt = min(CHUNK, N_EDGES - e0);          // 4096 or 3840: %4 == 0
        const int4* r4 = (const int4*)(rows + e0);
        for (int t = threadIdx.x; t < (cnt >> 2); t += 256) {
            int4 r = r4[t];
            atomicAdd(&counts[r.x], 1);
            atomicAdd(&counts[r.y], 1);
            atomicAdd(&counts[r.z], 1);
            atomicAdd(&counts[r.w], 1);
        }
    } else {
        int i = (blockIdx.x - NBLK) * 256 + threadIdx.x;
        const int nU4 = NUM_USERS * 16;
        float4 v = (i < nU4) ? ue4[i] : ie4[i - nU4];
        tab[i] = pk4_fp8(v.x, v.y, v.z, v.w);
    }
}

// ---------------------------------------------------------------------------
// scanA: per-512-row block sums of counts -> btotal[293]
// ---------------------------------------------------------------------------
__global__ __launch_bounds__(512) void k_scanA(const int* __restrict__ counts,
                                               int* __restrict__ btotal) {
    __shared__ int wsum[8];
    int tid = threadIdx.x;
    int i = (blockIdx.x << 9) + tid;
    int v = (i < N_NODES) ? counts[i] : 0;
    int incl = scan_incl<512>(v, tid, wsum);
    if (tid == 511) btotal[blockIdx.x] = incl;
}

// ---------------------------------------------------------------------------
// scanB: every block scans btotal in-LDS for its base, then scans its own
// 512 counts -> startArr (exclusive) and curArr (running fill cursors).
// ---------------------------------------------------------------------------
__global__ __launch_bounds__(512) void k_scanB(const int* __restrict__ counts,
                                               const int* __restrict__ btotal,
                                               int* __restrict__ startArr,
                                               int* __restrict__ curArr) {
    __shared__ int wsum[8];
    __shared__ int s_base;
    int k = blockIdx.x;
    int tid = threadIdx.x;
    int bt = (tid < NBKT) ? btotal[tid] : 0;
    int bincl = scan_incl<512>(bt, tid, wsum);
    if (tid == k) s_base = bincl - bt;               // block's global prefix
    int i = (k << 9) + tid;
    int v = (i < N_NODES) ? counts[i] : 0;
    int incl = scan_incl<512>(v, tid, wsum);         // entry barrier covers s_base
    if (i < N_NODES) {
        int sa = s_base + incl - v;
        startArr[i] = sa;
        curArr[i]   = sa;
    }
}

// ---------------------------------------------------------------------------
// fill: one pass over (rows, cols, vals); pos = atomicAdd(curArr[row]).
// 8 B scatter into edges (19.2 MB) is absorbed by the 32 MB aggregate L2,
// evicted once per 64 B line. Replaces p1c + p2 (57.6 MB staged traffic).
// Within-row edge order becomes arbitrary (fp reorder noise ~1e-7, ok).
// ---------------------------------------------------------------------------
__global__ __launch_bounds__(512) void k_fill(const int* __restrict__ rows,
                                              const int* __restrict__ cols,
                                              const float* __restrict__ vals,
                                              int* __restrict__ curArr,
                                              int2* __restrict__ edges) {
    int e0 = blockIdx.x * CHUNK;
    int cnt = min(CHUNK, N_EDGES - e0);              // %4 == 0 always
    const int4*   r4 = (const int4*)  (rows + e0);
    const int4*   c4 = (const int4*)  (cols + e0);
    const float4* v4 = (const float4*)(vals + e0);
    for (int t = threadIdx.x; t < (cnt >> 2); t += 512) {
        int4 r = r4[t];
        int4 c = c4[t];
        float4 v = v4[t];
        int p0 = atomicAdd(&curArr[r.x], 1);
        edges[p0] = make_int2(c.x, __float_as_int(v.x));
        int p1 = atomicAdd(&curArr[r.y], 1);
        edges[p1] = make_int2(c.y, __float_as_int(v.y));
        int p2 = atomicAdd(&curArr[r.z], 1);
        edges[p2] = make_int2(c.z, __float_as_int(v.z));
        int p3 = atomicAdd(&curArr[r.w], 1);
        edges[p3] = make_int2(c.w, __float_as_int(v.w));
    }
}

// ---------------------------------------------------------------------------
// Quad-gather SpMM core (fp8 table).
// 64 lanes = 4 groups of 16; group g handles edges 4q+g. Lane li in a group
// reads one uint (4 fp8 dims) -> 16 lanes cover the 64 B row. ONE vmem
// instruction fetches FOUR edges' rows. Bound by random-gather line traffic
// (~1 row-miss per edge) -- at the structural floor; do not grow flights.
// ---------------------------------------------------------------------------
template<int P>
__device__ __forceinline__ void qflight(const int2* __restrict__ edges,
                                        const unsigned* __restrict__ tab,
                                        int s, int q, int g, int li,
                                        float& a0, float& a1, float& a2, float& a3) {
    unsigned u[P];
    float    v[P];
    #pragma unroll
    for (int t = 0; t < P; t++) {
        int2 e = edges[s + 4 * (q + t) + g];   // 16 lanes share addr -> 1 line
        v[t] = __int_as_float(e.y);
        u[t] = tab[(size_t)e.x * 16 + li];     // 16 lanes x 4B = full 64B row
    }
    #pragma unroll
    for (int t = 0; t < P; t++) {
        floatx2 lo = __builtin_amdgcn_cvt_pk_f32_fp8(u[t], false);
        floatx2 hi = __builtin_amdgcn_cvt_pk_f32_fp8(u[t], true);
        a0 = fmaf(v[t], lo.x, a0);
        a1 = fmaf(v[t], lo.y, a1);
        a2 = fmaf(v[t], hi.x, a2);
        a3 = fmaf(v[t], hi.y, a3);
    }
}

__device__ __forceinline__ void spmm_row_q(const int2* __restrict__ edges,
                                           const unsigned* __restrict__ tab,
                                           int s, int n, int g, int li,
                                           float& a0, float& a1, float& a2, float& a3) {
    int nq = n >> 2, rem = n & 3;
    int q = 0;
    for (; q + 8 <= nq; q += 8)
        qflight<8>(edges, tab, s, q, g, li, a0, a1, a2, a3);
    if (nq - q >= 4) { qflight<4>(edges, tab, s, q, g, li, a0, a1, a2, a3); q += 4; }
    if (nq - q >= 2) { qflight<2>(edges, tab, s, q, g, li, a0, a1, a2, a3); q += 2; }
    if (nq - q >= 1) { qflight<1>(edges, tab, s, q, g, li, a0, a1, a2, a3); q += 1; }
    if (rem) {                                  // last 1-3 edges, masked
        int gi = (g < rem) ? g : 0;
        int2 e = edges[s + 4 * nq + gi];
        float v = (g < rem) ? __int_as_float(e.y) : 0.f;
        unsigned u = tab[(size_t)e.x * 16 + li];
        floatx2 lo = __builtin_amdgcn_cvt_pk_f32_fp8(u, false);
        floatx2 hi = __builtin_amdgcn_cvt_pk_f32_fp8(u, true);
        a0 = fmaf(v, lo.x, a0);
        a1 = fmaf(v, lo.y, a1);
        a2 = fmaf(v, hi.x, a2);
        a3 = fmaf(v, hi.y, a3);
    }
}

// ---------------------------------------------------------------------------
// Gather SpMM (fp8): one wave per row, quad-gather layout.
// ---------------------------------------------------------------------------
__global__ __launch_bounds__(256) void k_spmm_csr(const int* __restrict__ startArr,
                                                  const int* __restrict__ counts,
                                                  const int2* __restrict__ edges,
                                                  const unsigned* __restrict__ cur,
                                                  unsigned* __restrict__ nxt) {
    int row  = blockIdx.x * 4 + (threadIdx.x >> 6);
    if (row >= N_NODES) return;
    row = __builtin_amdgcn_readfirstlane(row);
    int lane = threadIdx.x & 63;
    int g  = lane >> 4;
    int li = lane & 15;
    int s = __builtin_amdgcn_readfirstlane(startArr[row]);
    int n = __builtin_amdgcn_readfirstlane(counts[row]);

    float a0 = 0.f, a1 = 0.f, a2 = 0.f, a3 = 0.f;
    spmm_row_q(edges, cur, s, n, g, li, a0, a1, a2, a3);

    // combine the 4 edge-groups (butterfly over lane^16, lane^32)
    a0 += __shfl_xor(a0, 16); a0 += __shfl_xor(a0, 32);
    a1 += __shfl_xor(a1, 16); a1 += __shfl_xor(a1, 32);
    a2 += __shfl_xor(a2, 16); a2 += __shfl_xor(a2, 32);
    a3 += __shfl_xor(a3, 16); a3 += __shfl_xor(a3, 32);
    if (g == 0)
        nxt[(size_t)row * 16 + li] = pk4_fp8(a0, a1, a2, a3);
}

// ---------------------------------------------------------------------------
// Fused layer-3 gathers + layer-2 + layer-1 contributions at selected rows.
// SOLE writer of vsel (pure store; layer-0 is added inside k_mlp).
// ---------------------------------------------------------------------------
__global__ __launch_bounds__(256) void k_spmm_sel(const int* __restrict__ users,
                                                  const int* __restrict__ items,
                                                  const int* __restrict__ startArr,
                                                  const int* __restrict__ counts,
                                                  const int2* __restrict__ edges,
                                                  const unsigned* __restrict__ cur,
                                                  const unsigned* __restrict__ lay1,
                                                  float* __restrict__ vsel) {
    int wave = blockIdx.x * 4 + (threadIdx.x >> 6);
    int lane = threadIdx.x & 63;
    int g  = lane >> 4;
    int li = lane & 15;
    int b, row, off;
    if (wave < BATCH) { b = wave;         row = users[b];             off = 0; }
    else              { b = wave - BATCH; row = NUM_USERS + items[b]; off = 64; }
    row = __builtin_amdgcn_readfirstlane(row);
    int s = __builtin_amdgcn_readfirstlane(startArr[row]);
    int n = __builtin_amdgcn_readfirstlane(counts[row]);

    float a0 = 0.f, a1 = 0.f, a2 = 0.f, a3 = 0.f;
    if (g == 0) {                          // layer-2 + layer-1 contributions
        unsigned u2 = cur [(size_t)row * 16 + li];
        unsigned u1 = lay1[(size_t)row * 16 + li];
        floatx2 lo2 = __builtin_amdgcn_cvt_pk_f32_fp8(u2, false);
        floatx2 hi2 = __builtin_amdgcn_cvt_pk_f32_fp8(u2, true);
        floatx2 lo1 = __builtin_amdgcn_cvt_pk_f32_fp8(u1, false);
        floatx2 hi1 = __builtin_amdgcn_cvt_pk_f32_fp8(u1, true);
        a0 = lo2.x + lo1.x; a1 = lo2.y + lo1.y;
        a2 = hi2.x + hi1.x; a3 = hi2.y + hi1.y;
    }
    spmm_row_q(edges, cur, s, n, g, li, a0, a1, a2, a3);

    a0 += __shfl_xor(a0, 16); a0 += __shfl_xor(a0, 32);
    a1 += __shfl_xor(a1, 16); a1 += __shfl_xor(a1, 32);
    a2 += __shfl_xor(a2, 16); a2 += __shfl_xor(a2, 32);
    a3 += __shfl_xor(a3, 16); a3 += __shfl_xor(a3, 32);
    if (g == 0) {
        float4* p = (float4*)(vsel + (size_t)b * 128 + off) + li;
        *p = make_float4(a0, a1, a2, a3);          // pure store, no RMW
    }
}

// ---------------------------------------------------------------------------
// MLP head v5: thread = (row, output-quarter); all register indices static.
// ---------------------------------------------------------------------------
__global__ __launch_bounds__(256) void k_mlp(const float* __restrict__ vsel,
                                             const int* __restrict__ users,
                                             const int* __restrict__ items,
                                             const float* __restrict__ ue,
                                             const float* __restrict__ ie,
                                             const float* __restrict__ W0,
                                             const float* __restrict__ b0,
                                             const float* __restrict__ W1,
                                             const float* __restrict__ b1,
                                             const float* __restrict__ Wa,
                                             const float* __restrict__ ba,
                                             float* __restrict__ out) {
    __shared__ float sW0[128 * 64];          // row-major, as given
    __shared__ float sW1[4 * 520];           // 4 panels of 16 rows, +8 skew
    __shared__ float sWa[32];
    __shared__ float sb0[64];
    __shared__ float sb1[32];

    for (int i = threadIdx.x; i < 128 * 64; i += 256) sW0[i] = W0[i];
    for (int i = threadIdx.x; i < 64 * 32; i += 256) {
        int k = i >> 5, j = i & 31;
        sW1[(k >> 4) * 520 + (k & 15) * 32 + j] = W1[i];
    }
    if (threadIdx.x < 32) sWa[threadIdx.x] = Wa[threadIdx.x];
    if (threadIdx.x < 64) sb0[threadIdx.x] = b0[threadIdx.x];
    if (threadIdx.x >= 64 && threadIdx.x < 96) sb1[threadIdx.x - 64] = b1[threadIdx.x - 64];
    float sba = ba[0];
    __syncthreads();

    int t = blockIdx.x * 256 + threadIdx.x;
    int b = t >> 2, sub = t & 3;                     // 4 threads per row
    const float4* v4  = (const float4*)(vsel + (size_t)b * 128);
    const float4* ue4 = (const float4*)(ue + (size_t)users[b] * 64);
    const float4* ie4 = (const float4*)(ie + (size_t)items[b] * 64);

    // h0s[j] = thread's 16 neurons (cols sub*16 .. +15), bias-initialized
    float h0s[16];
    {
        const float4* bb = (const float4*)&sb0[sub * 16];
        #pragma unroll
        for (int q = 0; q < 4; q++) {
            float4 bv = bb[q];
            h0s[q * 4 + 0] = bv.x; h0s[q * 4 + 1] = bv.y;
            h0s[q * 4 + 2] = bv.z; h0s[q * 4 + 3] = bv.w;
        }
    }

    #pragma unroll
    for (int k0 = 0; k0 < 32; k0++) {                // 4 inputs per iter
        float4 va = v4[k0];
        float4 ea = (k0 < 16) ? ue4[k0] : ie4[k0 - 16];
        float a[4] = { (va.x + ea.x) * 0.25f, (va.y + ea.y) * 0.25f,
                       (va.z + ea.z) * 0.25f, (va.w + ea.w) * 0.25f };
        #pragma unroll
        for (int r = 0; r < 4; r++) {
            const float4* w4 = (const float4*)&sW0[(k0 * 4 + r) * 64 + sub * 16];
            float ar = a[r];
            #pragma unroll
            for (int q = 0; q < 4; q++) {
                float4 wv = w4[q];
                h0s[q * 4 + 0] = fmaf(ar, wv.x, h0s[q * 4 + 0]);
                h0s[q * 4 + 1] = fmaf(ar, wv.y, h0s[q * 4 + 1]);
                h0s[q * 4 + 2] = fmaf(ar, wv.z, h0s[q * 4 + 2]);
                h0s[q * 4 + 3] = fmaf(ar, wv.w, h0s[q * 4 + 3]);
            }
        }
    }
    #pragma unroll
    for (int j = 0; j < 16; j++) h0s[j] = fmaxf(h0s[j], 0.f);

    // h1 partials from this thread's 16 h0 rows (W1 rows sub*16..+15)
    float h1p[32];
    #pragma unroll
    for (int j = 0; j < 32; j++) h1p[j] = 0.f;
    #pragma unroll
    for (int kk = 0; kk < 16; kk++) {
        float a = h0s[kk];
        const float4* w4 = (const float4*)&sW1[sub * 520 + kk * 32];
        #pragma unroll
        for (int q = 0; q < 8; q++) {
            float4 wv = w4[q];
            h1p[q * 4 + 0] = fmaf(a, wv.x, h1p[q * 4 + 0]);
            h1p[q * 4 + 1] = fmaf(a, wv.y, h1p[q * 4 + 1]);
            h1p[q * 4 + 2] = fmaf(a, wv.z, h1p[q * 4 + 2]);
            h1p[q * 4 + 3] = fmaf(a, wv.w, h1p[q * 4 + 3]);
        }
    }
    // reduce partials across the 4 subs (quad stays inside the wave)
    #pragma unroll
    for (int j = 0; j < 32; j++) {
        h1p[j] += __shfl_xor(h1p[j], 1);
        h1p[j] += __shfl_xor(h1p[j], 2);
    }

    float logit = sba;
    #pragma unroll
    for (int j = 0; j < 32; j++)
        logit = fmaf(fmaxf(h1p[j] + sb1[j], 0.f), sWa[j], logit);

    if (sub == 0) out[b] = 1.0f / (1.0f + expf(-logit));
}

// ---------------------------------------------------------------------------
extern "C" void kernel_launch(void* const* d_in, const int* in_sizes, int n_in,
                              void* d_out, int out_size, void* d_ws, size_t ws_size,
                              hipStream_t stream) {
    const int*   users = (const int*)  d_in[0];
    const int*   items = (const int*)  d_in[1];
    const int*   rows  = (const int*)  d_in[2];
    const int*   cols  = (const int*)  d_in[3];
    const float* vals  = (const float*)d_in[4];
    const float* ue    = (const float*)d_in[5];
    const float* ie    = (const float*)d_in[6];
    const float* W0    = (const float*)d_in[7];
    const float* b0    = (const float*)d_in[8];
    const float* W1    = (const float*)d_in[9];
    const float* b1    = (const float*)d_in[10];
    const float* Wa    = (const float*)d_in[11];
    const float* ba    = (const float*)d_in[12];
    float* out = (float*)d_out;

    char* ws = (char*)d_ws;
    unsigned* tabA8 = (unsigned*)ws;  ws += (size_t)N_NODES * 64;                // 9.6 MB
    unsigned* tabB8 = (unsigned*)ws;  ws += (size_t)N_NODES * 64;                // 9.6 MB
    float* vsel = (float*)ws;         ws += (size_t)BATCH * 128 * 4;             // 8.39 MB
    int2*  edges  = (int2*)ws;        ws += (size_t)N_EDGES * 8;                 // 19.2 MB
    int* counts   = (int*)ws;         ws += N_NODES * 4;
    int* startArr = (int*)ws;         ws += N_NODES * 4;
    int* curArr   = (int*)ws;         ws += N_NODES * 4;
    int* btotal   = (int*)ws;         ws += NBKT * 4;

    // zero the histogram (ordered on stream, graph-capturable)
    hipMemsetAsync(counts, 0, (size_t)N_NODES * 4, stream);

    // fp8 table + global-atomic row histogram (fused, one dispatch)
    k_prep<<<NBLK + CONCAT_BLKS, 256, 0, stream>>>(
        (const float4*)ue, (const float4*)ie, tabA8, rows, counts);

    // ---- CSR build: counts -> startArr/curArr -> atomic fill ----
    k_scanA<<<NBKT, 512, 0, stream>>>(counts, btotal);
    k_scanB<<<NBKT, 512, 0, stream>>>(counts, btotal, startArr, curArr);
    k_fill<<<NBLK, 512, 0, stream>>>(rows, cols, vals, curArr, edges);

    // layer 1: A -> B (writes every row; no memset needed)
    k_spmm_csr<<<(N_NODES + 3) / 4, 256, 0, stream>>>(startArr, counts, edges, tabA8, tabB8);

    // layer 2: B -> A  (tabB8 stays intact for the fused sel below)
    k_spmm_csr<<<(N_NODES + 3) / 4, 256, 0, stream>>>(startArr, counts, edges, tabB8, tabA8);

    // layer 3 gathers + layer-2 + layer-1 adds at selected rows (fused);
    // sole writer of vsel
    k_spmm_sel<<<(2 * BATCH) / 4, 256, 0, stream>>>(users, items, startArr,
                                                    counts, edges, tabA8, tabB8, vsel);

    // MLP head: 4 threads per row, layer-0 gather fused, no scratch
    k_mlp<<<(BATCH * 4) / 256, 256, 0, stream>>>(vsel, users, items, ue, ie,
                                                 W0, b0, W1, b1, Wa, ba, out);
}

// Round 8
// 439.335 us; speedup vs baseline: 1.2099x; 1.2099x over previous
//
#include <hip/hip_runtime.h>
#include <math.h>

#define NUM_USERS 100000
#define NUM_ITEMS 50000
#define N_NODES   150000   // NUM_USERS + NUM_ITEMS
#define LATENT    64
#define N_EDGES   2400000
#define BATCH     16384

// Multisplit fill: 4096-edge chunks, 512-row buckets
#define CHUNK 4096
#define NBLK  ((N_EDGES + CHUNK - 1) / CHUNK)   // 586
#define NBKT  ((N_NODES + 511) / 512)           // 293

typedef __attribute__((ext_vector_type(2))) float floatx2;

// fp8 e4m3 pack/unpack via gfx950 HW converters (encode+decode self-consistent)
__device__ __forceinline__ unsigned pk4_fp8(float a, float b, float c, float d) {
    int u = __builtin_amdgcn_cvt_pk_fp8_f32(a, b, 0, false);
    u     = __builtin_amdgcn_cvt_pk_fp8_f32(c, d, u, true);
    return (unsigned)u;
}

// ---------------------------------------------------------------------------
// Inclusive wave-hierarchical scan across NT threads (3 barriers).
// wsums = LDS scratch of NT/64 ints. Entry barrier protects prior wsums use.
// ---------------------------------------------------------------------------
template<int NT>
__device__ __forceinline__ int scan_incl(int v, int tid, int* wsums) {
    int lane = tid & 63, wid = tid >> 6;
    __syncthreads();
    int x = v;
    #pragma unroll
    for (int d = 1; d < 64; d <<= 1) {
        int y = __shfl_up(x, d);
        if (lane >= d) x += y;
    }
    if (lane == 63) wsums[wid] = x;
    __syncthreads();
    constexpr int NW = NT / 64;
    if (wid == 0) {
        int w = (lane < NW) ? wsums[lane] : 0;
        #pragma unroll
        for (int d = 1; d < NW; d <<= 1) {
            int y = __shfl_up(w, d);
            if (lane >= d) w += y;
        }
        if (lane < NW) wsums[lane] = w;
    }
    __syncthreads();
    return x + (wid ? wsums[wid - 1] : 0);
}

// ---------------------------------------------------------------------------
// Fused prep: [blocks 0..NBLK-1]  chunk bucket-hist -> cmat[bucket][block]
//                                 + global-atomic per-ROW histogram (counts,
//                                 pre-zeroed; ~16 hits/counter, no hot spot)
//             [blocks NBLK.. ]    tab = fp8(concat(user_emb, item_emb))
// ---------------------------------------------------------------------------
#define CONCAT_BLKS ((N_NODES * 16) / 256)      // 9375
__global__ __launch_bounds__(256) void k_prep(const float4* __restrict__ ue4,
                                              const float4* __restrict__ ie4,
                                              unsigned* __restrict__ tab,
                                              const int* __restrict__ rows,
                                              int* __restrict__ cmat,
                                              int* __restrict__ counts) {
    if (blockIdx.x < NBLK) {
        __shared__ int hist[NBKT];
        for (int i = threadIdx.x; i < NBKT; i += 256) hist[i] = 0;
        __syncthreads();
        int e0 = blockIdx.x * CHUNK;
        int cnt = min(CHUNK, N_EDGES - e0);          // 4096 or 3840: %4 == 0
        const int4* r4 = (const int4*)(rows + e0);
        for (int t = threadIdx.x; t < (cnt >> 2); t += 256) {
            int4 r = r4[t];
            atomicAdd(&hist[r.x >> 9], 1);
            atomicAdd(&hist[r.y >> 9], 1);
            atomicAdd(&hist[r.z >> 9], 1);
            atomicAdd(&hist[r.w >> 9], 1);
            atomicAdd(&counts[r.x], 1);              // row degree (global)
            atomicAdd(&counts[r.y], 1);
            atomicAdd(&counts[r.z], 1);
            atomicAdd(&counts[r.w], 1);
        }
        __syncthreads();
        for (int i = threadIdx.x; i < NBKT; i += 256)
            cmat[i * NBLK + blockIdx.x] = hist[i];
    } else {
        int i = (blockIdx.x - NBLK) * 256 + threadIdx.x;
        const int nU4 = NUM_USERS * 16;
        float4 v = (i < nU4) ? ue4[i] : ie4[i - nU4];
        tab[i] = pk4_fp8(v.x, v.y, v.z, v.w);
    }
}

// ---------------------------------------------------------------------------
// Multisplit p1b: per-bucket exclusive scan over blocks (hierarchical wave
// scan). Saves raw counts to bcnt for p1c; emits bucket total.
// ---------------------------------------------------------------------------
__global__ __launch_bounds__(1024) void k_p1b(int* __restrict__ cmat,
                                              int* __restrict__ bcnt,
                                              int* __restrict__ btotal) {
    __shared__ int wsum[16];
    int k = blockIdx.x;
    int tid = threadIdx.x;
    int lane = tid & 63, wid = tid >> 6;
    int v = (tid < NBLK) ? cmat[k * NBLK + tid] : 0;
    if (tid < NBLK) bcnt[k * NBLK + tid] = v;        // raw counts for p1c
    int x = v;
    #pragma unroll
    for (int d = 1; d < 64; d <<= 1) {
        int y = __shfl_up(x, d);
        if (lane >= d) x += y;
    }
    if (lane == 63) wsum[wid] = x;
    __syncthreads();
    if (wid == 0 && lane < 16) {
        int w = wsum[lane];
        #pragma unroll
        for (int d = 1; d < 16; d <<= 1) {
            int y = __shfl_up(w, d);
            if (lane >= d) w += y;
        }
        wsum[lane] = w;
    }
    __syncthreads();
    int incl = x + (wid ? wsum[wid - 1] : 0);
    if (tid < NBLK) cmat[k * NBLK + tid] = incl - v; // exclusive
    if (tid == 1023) btotal[k] = incl;               // padding adds 0
}

// ---------------------------------------------------------------------------
// Multisplit p1c (512 thr): bin records in LDS using p1b's saved counts,
// flush bucket-contiguous runs at exact offsets. Bucket bases computed
// in-LDS from btotal. Zero global atomics.
// Record: x = col(18b) | rowLo(9b)<<18 ; y = fp32 val bits.
// ---------------------------------------------------------------------------
__global__ __launch_bounds__(512) void k_p1c(const int* __restrict__ rows,
                                             const int* __restrict__ cols,
                                             const float* __restrict__ vals,
                                             const int* __restrict__ offs,
                                             const int* __restrict__ bcnt,
                                             const int* __restrict__ btotal,
                                             int2* __restrict__ staged) {
    __shared__ int hist[NBKT];
    __shared__ int lstart[NBKT];
    __shared__ int cursor[NBKT];
    __shared__ int soffs[NBKT];
    __shared__ int wsum[8];
    __shared__ int2 st[CHUNK];
    __shared__ unsigned short bkt16[CHUNK];

    int tid = threadIdx.x;
    int e0 = blockIdx.x * CHUNK;
    int cnt = min(CHUNK, N_EDGES - e0);              // %4 == 0 always

    // bucket bases from btotal (global prefix), chunk-local hist from bcnt
    int bt = (tid < NBKT) ? btotal[tid] : 0;
    int bincl = scan_incl<512>(bt, tid, wsum);       // inclusive
    int h = 0;
    if (tid < NBKT) {
        h = bcnt[tid * NBLK + blockIdx.x];
        hist[tid] = h;
        cursor[tid] = 0;
        soffs[tid] = offs[tid * NBLK + blockIdx.x] + (bincl - bt);  // + bbase
    }
    // chunk-local exclusive starts
    int hincl = scan_incl<512>(h, tid, wsum);
    if (tid < NBKT) lstart[tid] = hincl - h;
    __syncthreads();

    // bin into LDS staging (vectorized 4-edge input stream)
    const int4*   r4 = (const int4*)  (rows + e0);
    const int4*   c4 = (const int4*)  (cols + e0);
    const float4* v4 = (const float4*)(vals + e0);
    for (int t = tid; t < (cnt >> 2); t += 512) {
        int4 r = r4[t];
        int4 c = c4[t];
        float4 v = v4[t];
        int b0 = r.x >> 9, b1 = r.y >> 9, b2 = r.z >> 9, b3 = r.w >> 9;
        int p0 = lstart[b0] + atomicAdd(&cursor[b0], 1);
        st[p0] = make_int2(c.x | ((r.x & 511) << 18), __float_as_int(v.x));
        bkt16[p0] = (unsigned short)b0;
        int p1 = lstart[b1] + atomicAdd(&cursor[b1], 1);
        st[p1] = make_int2(c.y | ((r.y & 511) << 18), __float_as_int(v.y));
        bkt16[p1] = (unsigned short)b1;
        int p2 = lstart[b2] + atomicAdd(&cursor[b2], 1);
        st[p2] = make_int2(c.z | ((r.z & 511) << 18), __float_as_int(v.z));
        bkt16[p2] = (unsigned short)b2;
        int p3 = lstart[b3] + atomicAdd(&cursor[b3], 1);
        st[p3] = make_int2(c.w | ((r.w & 511) << 18), __float_as_int(v.w));
        bkt16[p3] = (unsigned short)b3;
    }
    __syncthreads();
    // flush: consecutive threads in a bucket write consecutive global addrs
    for (int t = tid; t < cnt; t += 512) {
        int b = bkt16[t];
        staged[soffs[b] + (t - lstart[b])] = st[t];
    }
}

// ---------------------------------------------------------------------------
// p2lite (512 thr): one block per bucket. lstart comes from the GLOBAL row
// histogram (coalesced 2 KB read) instead of a histogram pass over staged
// -> reads staged ONCE (round-6 p2 read it twice). Scatter stays inside the
// block's ~8 KB bucket segment (single-XCD, L2-coalesced -- the safe kind).
// Emits startArr; counts already global from k_prep.
// ---------------------------------------------------------------------------
__global__ __launch_bounds__(512) void k_p2lite(const int* __restrict__ btotal,
                                                const int* __restrict__ counts,
                                                const int2* __restrict__ staged,
                                                int2* __restrict__ edges,
                                                int* __restrict__ startArr) {
    __shared__ int lstart[512];
    __shared__ int curso[512];
    __shared__ int wsum[8];
    __shared__ int s_base, s_end;
    int k = blockIdx.x;
    int tid = threadIdx.x;
    int rowBase = k << 9;
    int i = rowBase + tid;

    int bt = (tid < NBKT) ? btotal[tid] : 0;
    int bincl = scan_incl<512>(bt, tid, wsum);
    if (tid == k) { s_base = bincl - bt; s_end = bincl; }
    int h = (i < N_NODES) ? counts[i] : 0;
    int hincl = scan_incl<512>(h, tid, wsum);        // entry barrier covers s_base
    lstart[tid] = hincl - h;
    curso[tid] = 0;
    __syncthreads();
    int base = s_base;
    int cnt  = s_end - base;

    for (int t = tid; t < cnt; t += 512) {
        int2 rec = staged[base + t];
        int rl = ((unsigned)rec.x) >> 18;
        int c  = rec.x & 0x3FFFF;
        int off = lstart[rl] + atomicAdd(&curso[rl], 1);
        edges[base + off] = make_int2(c, rec.y);
    }
    if (i < N_NODES && tid < 512) startArr[i] = base + lstart[tid];
}

// ---------------------------------------------------------------------------
// Quad-gather SpMM core (fp8 table), NT-templated loads.
// 64 lanes = 4 groups of 16; group g handles edges 4q+g; ONE vmem fetches
// FOUR edges' rows. NTL=1 uses nontemporal loads on edges+table (L1-bypass
// probe; layer 1 only -- within-run A/B vs layer 2).
// ---------------------------------------------------------------------------
template<int NTL>
__device__ __forceinline__ int2 ld_e(const int2* p) {
    if (NTL) {
        long long raw = __builtin_nontemporal_load((const long long*)p);
        int2 e; e.x = (int)(raw & 0xffffffffLL); e.y = (int)(raw >> 32);
        return e;
    }
    return *p;
}
template<int NTL>
__device__ __forceinline__ unsigned ld_t(const unsigned* p) {
    return NTL ? __builtin_nontemporal_load(p) : *p;
}

template<int P, int NTL>
__device__ __forceinline__ void qflight(const int2* __restrict__ edges,
                                        const unsigned* __restrict__ tab,
                                        int s, int q, int g, int li,
                                        float& a0, float& a1, float& a2, float& a3) {
    unsigned u[P];
    float    v[P];
    #pragma unroll
    for (int t = 0; t < P; t++) {
        int2 e = ld_e<NTL>(&edges[s + 4 * (q + t) + g]);
        v[t] = __int_as_float(e.y);
        u[t] = ld_t<NTL>(&tab[(size_t)e.x * 16 + li]);
    }
    #pragma unroll
    for (int t = 0; t < P; t++) {
        floatx2 lo = __builtin_amdgcn_cvt_pk_f32_fp8(u[t], false);
        floatx2 hi = __builtin_amdgcn_cvt_pk_f32_fp8(u[t], true);
        a0 = fmaf(v[t], lo.x, a0);
        a1 = fmaf(v[t], lo.y, a1);
        a2 = fmaf(v[t], hi.x, a2);
        a3 = fmaf(v[t], hi.y, a3);
    }
}

template<int NTL>
__device__ __forceinline__ void spmm_row_q(const int2* __restrict__ edges,
                                           const unsigned* __restrict__ tab,
                                           int s, int n, int g, int li,
                                           float& a0, float& a1, float& a2, float& a3) {
    int nq = n >> 2, rem = n & 3;
    int q = 0;
    for (; q + 8 <= nq; q += 8)
        qflight<8, NTL>(edges, tab, s, q, g, li, a0, a1, a2, a3);
    if (nq - q >= 4) { qflight<4, NTL>(edges, tab, s, q, g, li, a0, a1, a2, a3); q += 4; }
    if (nq - q >= 2) { qflight<2, NTL>(edges, tab, s, q, g, li, a0, a1, a2, a3); q += 2; }
    if (nq - q >= 1) { qflight<1, NTL>(edges, tab, s, q, g, li, a0, a1, a2, a3); q += 1; }
    if (rem) {                                  // last 1-3 edges, masked
        int gi = (g < rem) ? g : 0;
        int2 e = ld_e<NTL>(&edges[s + 4 * nq + gi]);
        float v = (g < rem) ? __int_as_float(e.y) : 0.f;
        unsigned u = ld_t<NTL>(&tab[(size_t)e.x * 16 + li]);
        floatx2 lo = __builtin_amdgcn_cvt_pk_f32_fp8(u, false);
        floatx2 hi = __builtin_amdgcn_cvt_pk_f32_fp8(u, true);
        a0 = fmaf(v, lo.x, a0);
        a1 = fmaf(v, lo.y, a1);
        a2 = fmaf(v, hi.x, a2);
        a3 = fmaf(v, hi.y, a3);
    }
}

// ---------------------------------------------------------------------------
// Gather SpMM (fp8): one wave per row, quad-gather layout.
// ---------------------------------------------------------------------------
template<int NTL>
__global__ __launch_bounds__(256) void k_spmm_csr(const int* __restrict__ startArr,
                                                  const int* __restrict__ counts,
                                                  const int2* __restrict__ edges,
                                                  const unsigned* __restrict__ cur,
                                                  unsigned* __restrict__ nxt) {
    int row  = blockIdx.x * 4 + (threadIdx.x >> 6);
    if (row >= N_NODES) return;
    row = __builtin_amdgcn_readfirstlane(row);
    int lane = threadIdx.x & 63;
    int g  = lane >> 4;
    int li = lane & 15;
    int s = __builtin_amdgcn_readfirstlane(startArr[row]);
    int n = __builtin_amdgcn_readfirstlane(counts[row]);

    float a0 = 0.f, a1 = 0.f, a2 = 0.f, a3 = 0.f;
    spmm_row_q<NTL>(edges, cur, s, n, g, li, a0, a1, a2, a3);

    // combine the 4 edge-groups (butterfly over lane^16, lane^32)
    a0 += __shfl_xor(a0, 16); a0 += __shfl_xor(a0, 32);
    a1 += __shfl_xor(a1, 16); a1 += __shfl_xor(a1, 32);
    a2 += __shfl_xor(a2, 16); a2 += __shfl_xor(a2, 32);
    a3 += __shfl_xor(a3, 16); a3 += __shfl_xor(a3, 32);
    if (g == 0)
        nxt[(size_t)row * 16 + li] = pk4_fp8(a0, a1, a2, a3);
}

// ---------------------------------------------------------------------------
// Fused layer-3 gathers + layer-2 + layer-1 contributions at selected rows.
// SOLE writer of vsel (pure store; layer-0 is added inside k_mlp).
// ---------------------------------------------------------------------------
__global__ __launch_bounds__(256) void k_spmm_sel(const int* __restrict__ users,
                                                  const int* __restrict__ items,
                                                  const int* __restrict__ startArr,
                                                  const int* __restrict__ counts,
                                                  const int2* __restrict__ edges,
                                                  const unsigned* __restrict__ cur,
                                                  const unsigned* __restrict__ lay1,
                                                  float* __restrict__ vsel) {
    int wave = blockIdx.x * 4 + (threadIdx.x >> 6);
    int lane = threadIdx.x & 63;
    int g  = lane >> 4;
    int li = lane & 15;
    int b, row, off;
    if (wave < BATCH) { b = wave;         row = users[b];             off = 0; }
    else              { b = wave - BATCH; row = NUM_USERS + items[b]; off = 64; }
    row = __builtin_amdgcn_readfirstlane(row);
    int s = __builtin_amdgcn_readfirstlane(startArr[row]);
    int n = __builtin_amdgcn_readfirstlane(counts[row]);

    float a0 = 0.f, a1 = 0.f, a2 = 0.f, a3 = 0.f;
    if (g == 0) {                          // layer-2 + layer-1 contributions
        unsigned u2 = cur [(size_t)row * 16 + li];
        unsigned u1 = lay1[(size_t)row * 16 + li];
        floatx2 lo2 = __builtin_amdgcn_cvt_pk_f32_fp8(u2, false);
        floatx2 hi2 = __builtin_amdgcn_cvt_pk_f32_fp8(u2, true);
        floatx2 lo1 = __builtin_amdgcn_cvt_pk_f32_fp8(u1, false);
        floatx2 hi1 = __builtin_amdgcn_cvt_pk_f32_fp8(u1, true);
        a0 = lo2.x + lo1.x; a1 = lo2.y + lo1.y;
        a2 = hi2.x + hi1.x; a3 = hi2.y + hi1.y;
    }
    spmm_row_q<0>(edges, cur, s, n, g, li, a0, a1, a2, a3);

    a0 += __shfl_xor(a0, 16); a0 += __shfl_xor(a0, 32);
    a1 += __shfl_xor(a1, 16); a1 += __shfl_xor(a1, 32);
    a2 += __shfl_xor(a2, 16); a2 += __shfl_xor(a2, 32);
    a3 += __shfl_xor(a3, 16); a3 += __shfl_xor(a3, 32);
    if (g == 0) {
        float4* p = (float4*)(vsel + (size_t)b * 128 + off) + li;
        *p = make_float4(a0, a1, a2, a3);          // pure store, no RMW
    }
}

// ---------------------------------------------------------------------------
// MLP head v5: thread = (row, output-quarter); all register indices static.
// ---------------------------------------------------------------------------
__global__ __launch_bounds__(256) void k_mlp(const float* __restrict__ vsel,
                                             const int* __restrict__ users,
                                             const int* __restrict__ items,
                                             const float* __restrict__ ue,
                                             const float* __restrict__ ie,
                                             const float* __restrict__ W0,
                                             const float* __restrict__ b0,
                                             const float* __restrict__ W1,
                                             const float* __restrict__ b1,
                                             const float* __restrict__ Wa,
                                             const float* __restrict__ ba,
                                             float* __restrict__ out) {
    __shared__ float sW0[128 * 64];          // row-major, as given
    __shared__ float sW1[4 * 520];           // 4 panels of 16 rows, +8 skew
    __shared__ float sWa[32];
    __shared__ float sb0[64];
    __shared__ float sb1[32];

    for (int i = threadIdx.x; i < 128 * 64; i += 256) sW0[i] = W0[i];
    for (int i = threadIdx.x; i < 64 * 32; i += 256) {
        int k = i >> 5, j = i & 31;
        sW1[(k >> 4) * 520 + (k & 15) * 32 + j] = W1[i];
    }
    if (threadIdx.x < 32) sWa[threadIdx.x] = Wa[threadIdx.x];
    if (threadIdx.x < 64) sb0[threadIdx.x] = b0[threadIdx.x];
    if (threadIdx.x >= 64 && threadIdx.x < 96) sb1[threadIdx.x - 64] = b1[threadIdx.x - 64];
    float sba = ba[0];
    __syncthreads();

    int t = blockIdx.x * 256 + threadIdx.x;
    int b = t >> 2, sub = t & 3;                     // 4 threads per row
    const float4* v4  = (const float4*)(vsel + (size_t)b * 128);
    const float4* ue4 = (const float4*)(ue + (size_t)users[b] * 64);
    const float4* ie4 = (const float4*)(ie + (size_t)items[b] * 64);

    // h0s[j] = thread's 16 neurons (cols sub*16 .. +15), bias-initialized
    float h0s[16];
    {
        const float4* bb = (const float4*)&sb0[sub * 16];
        #pragma unroll
        for (int q = 0; q < 4; q++) {
            float4 bv = bb[q];
            h0s[q * 4 + 0] = bv.x; h0s[q * 4 + 1] = bv.y;
            h0s[q * 4 + 2] = bv.z; h0s[q * 4 + 3] = bv.w;
        }
    }

    #pragma unroll
    for (int k0 = 0; k0 < 32; k0++) {                // 4 inputs per iter
        float4 va = v4[k0];
        float4 ea = (k0 < 16) ? ue4[k0] : ie4[k0 - 16];
        float a[4] = { (va.x + ea.x) * 0.25f, (va.y + ea.y) * 0.25f,
                       (va.z + ea.z) * 0.25f, (va.w + ea.w) * 0.25f };
        #pragma unroll
        for (int r = 0; r < 4; r++) {
            const float4* w4 = (const float4*)&sW0[(k0 * 4 + r) * 64 + sub * 16];
            float ar = a[r];
            #pragma unroll
            for (int q = 0; q < 4; q++) {
                float4 wv = w4[q];
                h0s[q * 4 + 0] = fmaf(ar, wv.x, h0s[q * 4 + 0]);
                h0s[q * 4 + 1] = fmaf(ar, wv.y, h0s[q * 4 + 1]);
                h0s[q * 4 + 2] = fmaf(ar, wv.z, h0s[q * 4 + 2]);
                h0s[q * 4 + 3] = fmaf(ar, wv.w, h0s[q * 4 + 3]);
            }
        }
    }
    #pragma unroll
    for (int j = 0; j < 16; j++) h0s[j] = fmaxf(h0s[j], 0.f);

    // h1 partials from this thread's 16 h0 rows (W1 rows sub*16..+15)
    float h1p[32];
    #pragma unroll
    for (int j = 0; j < 32; j++) h1p[j] = 0.f;
    #pragma unroll
    for (int kk = 0; kk < 16; kk++) {
        float a = h0s[kk];
        const float4* w4 = (const float4*)&sW1[sub * 520 + kk * 32];
        #pragma unroll
        for (int q = 0; q < 8; q++) {
            float4 wv = w4[q];
            h1p[q * 4 + 0] = fmaf(a, wv.x, h1p[q * 4 + 0]);
            h1p[q * 4 + 1] = fmaf(a, wv.y, h1p[q * 4 + 1]);
            h1p[q * 4 + 2] = fmaf(a, wv.z, h1p[q * 4 + 2]);
            h1p[q * 4 + 3] = fmaf(a, wv.w, h1p[q * 4 + 3]);
        }
    }
    // reduce partials across the 4 subs (quad stays inside the wave)
    #pragma unroll
    for (int j = 0; j < 32; j++) {
        h1p[j] += __shfl_xor(h1p[j], 1);
        h1p[j] += __shfl_xor(h1p[j], 2);
    }

    float logit = sba;
    #pragma unroll
    for (int j = 0; j < 32; j++)
        logit = fmaf(fmaxf(h1p[j] + sb1[j], 0.f), sWa[j], logit);

    if (sub == 0) out[b] = 1.0f / (1.0f + expf(-logit));
}

// ---------------------------------------------------------------------------
extern "C" void kernel_launch(void* const* d_in, const int* in_sizes, int n_in,
                              void* d_out, int out_size, void* d_ws, size_t ws_size,
                              hipStream_t stream) {
    const int*   users = (const int*)  d_in[0];
    const int*   items = (const int*)  d_in[1];
    const int*   rows  = (const int*)  d_in[2];
    const int*   cols  = (const int*)  d_in[3];
    const float* vals  = (const float*)d_in[4];
    const float* ue    = (const float*)d_in[5];
    const float* ie    = (const float*)d_in[6];
    const float* W0    = (const float*)d_in[7];
    const float* b0    = (const float*)d_in[8];
    const float* W1    = (const float*)d_in[9];
    const float* b1    = (const float*)d_in[10];
    const float* Wa    = (const float*)d_in[11];
    const float* ba    = (const float*)d_in[12];
    float* out = (float*)d_out;

    char* ws = (char*)d_ws;
    unsigned* tabA8 = (unsigned*)ws;  ws += (size_t)N_NODES * 64;                // 9.6 MB
    unsigned* tabB8 = (unsigned*)ws;  ws += (size_t)N_NODES * 64;                // 9.6 MB
    float* vsel = (float*)ws;         ws += (size_t)BATCH * 128 * 4;             // 8.39 MB
    int2*  edges  = (int2*)ws;        ws += (size_t)N_EDGES * 8;                 // 19.2 MB
    int2*  staged = (int2*)ws;        ws += (size_t)N_EDGES * 8;                 // 19.2 MB
    int* counts   = (int*)ws;         ws += N_NODES * 4;
    int* startArr = (int*)ws;         ws += N_NODES * 4;
    int* cmat     = (int*)ws;         ws += (size_t)NBKT * NBLK * 4;             // 686 KB
    int* bcnt     = (int*)ws;         ws += (size_t)NBKT * NBLK * 4;             // 686 KB
    int* btotal   = (int*)ws;         ws += NBKT * 4;

    // zero the row histogram (stream-ordered, graph-capturable)
    hipMemsetAsync(counts, 0, (size_t)N_NODES * 4, stream);

    // fp8 table + chunk bucket-hist + global row-hist (fused, one dispatch)
    k_prep<<<NBLK + CONCAT_BLKS, 256, 0, stream>>>(
        (const float4*)ue, (const float4*)ie, tabA8, rows, cmat, counts);

    // ---- CSR build (multisplit; staged read ONCE in p2lite) ----
    k_p1b<<<NBKT, 1024, 0, stream>>>(cmat, bcnt, btotal);
    k_p1c<<<NBLK, 512, 0, stream>>>(rows, cols, vals, cmat, bcnt, btotal, staged);
    k_p2lite<<<NBKT, 512, 0, stream>>>(btotal, counts, staged, edges, startArr);

    // layer 1: A -> B  (NT-load probe arm)
    k_spmm_csr<1><<<(N_NODES + 3) / 4, 256, 0, stream>>>(startArr, counts, edges, tabA8, tabB8);

    // layer 2: B -> A  (control arm; tabB8 stays intact for fused sel)
    k_spmm_csr<0><<<(N_NODES + 3) / 4, 256, 0, stream>>>(startArr, counts, edges, tabB8, tabA8);

    // layer 3 gathers + layer-2 + layer-1 adds at selected rows (fused);
    // sole writer of vsel
    k_spmm_sel<<<(2 * BATCH) / 4, 256, 0, stream>>>(users, items, startArr,
                                                    counts, edges, tabA8, tabB8, vsel);

    // MLP head: 4 threads per row, layer-0 gather fused, no scratch
    k_mlp<<<(BATCH * 4) / 256, 256, 0, stream>>>(vsel, users, items, ue, ie,
                                                 W0, b0, W1, b1, Wa, ba, out);
}

// Round 9
// 314.316 us; speedup vs baseline: 1.6911x; 1.3977x over previous
//
#include <hip/hip_runtime.h>
#include <math.h>

#define NUM_USERS 100000
#define NUM_ITEMS 50000
#define N_NODES   150000   // NUM_USERS + NUM_ITEMS
#define LATENT    64
#define N_EDGES   2400000
#define BATCH     16384

// Multisplit fill: 4096-edge chunks, 512-row buckets
#define CHUNK 4096
#define NBLK  ((N_EDGES + CHUNK - 1) / CHUNK)   // 586
#define NBKT  ((N_NODES + 511) / 512)           // 293

typedef __attribute__((ext_vector_type(2))) float floatx2;

// fp8 e4m3 pack/unpack via gfx950 HW converters (encode+decode self-consistent)
__device__ __forceinline__ unsigned pk4_fp8(float a, float b, float c, float d) {
    int u = __builtin_amdgcn_cvt_pk_fp8_f32(a, b, 0, false);
    u     = __builtin_amdgcn_cvt_pk_fp8_f32(c, d, u, true);
    return (unsigned)u;
}

// ---------------------------------------------------------------------------
// Inclusive wave-hierarchical scan across NT threads (3 barriers).
// wsums = LDS scratch of NT/64 ints. Entry barrier protects prior wsums use.
// ---------------------------------------------------------------------------
template<int NT>
__device__ __forceinline__ int scan_incl(int v, int tid, int* wsums) {
    int lane = tid & 63, wid = tid >> 6;
    __syncthreads();
    int x = v;
    #pragma unroll
    for (int d = 1; d < 64; d <<= 1) {
        int y = __shfl_up(x, d);
        if (lane >= d) x += y;
    }
    if (lane == 63) wsums[wid] = x;
    __syncthreads();
    constexpr int NW = NT / 64;
    if (wid == 0) {
        int w = (lane < NW) ? wsums[lane] : 0;
        #pragma unroll
        for (int d = 1; d < NW; d <<= 1) {
            int y = __shfl_up(w, d);
            if (lane >= d) w += y;
        }
        if (lane < NW) wsums[lane] = w;
    }
    __syncthreads();
    return x + (wid ? wsums[wid - 1] : 0);
}

// ---------------------------------------------------------------------------
// Fused prep: [blocks 0..NBLK-1]  p1a bucket histogram -> cmat[bucket][block]
//             [blocks NBLK.. ]    tab = fp8(concat(user_emb, item_emb))
// NOTE (r7/r8 lesson): do NOT add global-atomic row counters here -- 2.4M
// device-scope atomics over 8 non-coherent XCDs cost ~1 HBM line each
// (~90 MB writes, +85 us). LDS histograms + multisplit is the right shape.
// ---------------------------------------------------------------------------
#define CONCAT_BLKS ((N_NODES * 16) / 256)      // 9375
__global__ __launch_bounds__(256) void k_prep(const float4* __restrict__ ue4,
                                              const float4* __restrict__ ie4,
                                              unsigned* __restrict__ tab,
                                              const int* __restrict__ rows,
                                              int* __restrict__ cmat) {
    if (blockIdx.x < NBLK) {
        __shared__ int hist[NBKT];
        for (int i = threadIdx.x; i < NBKT; i += 256) hist[i] = 0;
        __syncthreads();
        int e0 = blockIdx.x * CHUNK;
        int cnt = min(CHUNK, N_EDGES - e0);          // 4096 or 3840: %4 == 0
        const int4* r4 = (const int4*)(rows + e0);
        for (int t = threadIdx.x; t < (cnt >> 2); t += 256) {
            int4 r = r4[t];
            atomicAdd(&hist[r.x >> 9], 1);
            atomicAdd(&hist[r.y >> 9], 1);
            atomicAdd(&hist[r.z >> 9], 1);
            atomicAdd(&hist[r.w >> 9], 1);
        }
        __syncthreads();
        for (int i = threadIdx.x; i < NBKT; i += 256)
            cmat[i * NBLK + blockIdx.x] = hist[i];
    } else {
        int i = (blockIdx.x - NBLK) * 256 + threadIdx.x;
        const int nU4 = NUM_USERS * 16;
        float4 v = (i < nU4) ? ue4[i] : ie4[i - nU4];
        tab[i] = pk4_fp8(v.x, v.y, v.z, v.w);
    }
}

// ---------------------------------------------------------------------------
// Multisplit p1b: per-bucket exclusive scan over blocks (hierarchical wave
// scan). Saves raw counts to bcnt for p1c; emits bucket total.
// ---------------------------------------------------------------------------
__global__ __launch_bounds__(1024) void k_p1b(int* __restrict__ cmat,
                                              int* __restrict__ bcnt,
                                              int* __restrict__ btotal) {
    __shared__ int wsum[16];
    int k = blockIdx.x;
    int tid = threadIdx.x;
    int lane = tid & 63, wid = tid >> 6;
    int v = (tid < NBLK) ? cmat[k * NBLK + tid] : 0;
    if (tid < NBLK) bcnt[k * NBLK + tid] = v;        // raw counts for p1c
    int x = v;
    #pragma unroll
    for (int d = 1; d < 64; d <<= 1) {
        int y = __shfl_up(x, d);
        if (lane >= d) x += y;
    }
    if (lane == 63) wsum[wid] = x;
    __syncthreads();
    if (wid == 0 && lane < 16) {
        int w = wsum[lane];
        #pragma unroll
        for (int d = 1; d < 16; d <<= 1) {
            int y = __shfl_up(w, d);
            if (lane >= d) w += y;
        }
        wsum[lane] = w;
    }
    __syncthreads();
    int incl = x + (wid ? wsum[wid - 1] : 0);
    if (tid < NBLK) cmat[k * NBLK + tid] = incl - v; // exclusive
    if (tid == 1023) btotal[k] = incl;               // padding adds 0
}

// ---------------------------------------------------------------------------
// Multisplit p1c (512 thr): bin records in LDS using p1b's saved counts,
// flush bucket-contiguous runs at exact offsets. Bucket bases computed
// in-LDS from btotal. Zero global atomics.
// Record: x = col(18b) | rowLo(9b)<<18 ; y = fp32 val bits.
// ---------------------------------------------------------------------------
__global__ __launch_bounds__(512) void k_p1c(const int* __restrict__ rows,
                                             const int* __restrict__ cols,
                                             const float* __restrict__ vals,
                                             const int* __restrict__ offs,
                                             const int* __restrict__ bcnt,
                                             const int* __restrict__ btotal,
                                             int2* __restrict__ staged) {
    __shared__ int hist[NBKT];
    __shared__ int lstart[NBKT];
    __shared__ int cursor[NBKT];
    __shared__ int soffs[NBKT];
    __shared__ int wsum[8];
    __shared__ int2 st[CHUNK];
    __shared__ unsigned short bkt16[CHUNK];

    int tid = threadIdx.x;
    int e0 = blockIdx.x * CHUNK;
    int cnt = min(CHUNK, N_EDGES - e0);              // %4 == 0 always

    // bucket bases from btotal (global prefix), chunk-local hist from bcnt
    int bt = (tid < NBKT) ? btotal[tid] : 0;
    int bincl = scan_incl<512>(bt, tid, wsum);       // inclusive
    int h = 0;
    if (tid < NBKT) {
        h = bcnt[tid * NBLK + blockIdx.x];
        hist[tid] = h;
        cursor[tid] = 0;
        soffs[tid] = offs[tid * NBLK + blockIdx.x] + (bincl - bt);  // + bbase
    }
    // chunk-local exclusive starts
    int hincl = scan_incl<512>(h, tid, wsum);
    if (tid < NBKT) lstart[tid] = hincl - h;
    __syncthreads();

    // bin into LDS staging (vectorized 4-edge input stream)
    const int4*   r4 = (const int4*)  (rows + e0);
    const int4*   c4 = (const int4*)  (cols + e0);
    const float4* v4 = (const float4*)(vals + e0);
    for (int t = tid; t < (cnt >> 2); t += 512) {
        int4 r = r4[t];
        int4 c = c4[t];
        float4 v = v4[t];
        int b0 = r.x >> 9, b1 = r.y >> 9, b2 = r.z >> 9, b3 = r.w >> 9;
        int p0 = lstart[b0] + atomicAdd(&cursor[b0], 1);
        st[p0] = make_int2(c.x | ((r.x & 511) << 18), __float_as_int(v.x));
        bkt16[p0] = (unsigned short)b0;
        int p1 = lstart[b1] + atomicAdd(&cursor[b1], 1);
        st[p1] = make_int2(c.y | ((r.y & 511) << 18), __float_as_int(v.y));
        bkt16[p1] = (unsigned short)b1;
        int p2 = lstart[b2] + atomicAdd(&cursor[b2], 1);
        st[p2] = make_int2(c.z | ((r.z & 511) << 18), __float_as_int(v.z));
        bkt16[p2] = (unsigned short)b2;
        int p3 = lstart[b3] + atomicAdd(&cursor[b3], 1);
        st[p3] = make_int2(c.w | ((r.w & 511) << 18), __float_as_int(v.w));
        bkt16[p3] = (unsigned short)b3;
    }
    __syncthreads();
    // flush: consecutive threads in a bucket write consecutive global addrs
    for (int t = tid; t < cnt; t += 512) {
        int b = bkt16[t];
        staged[soffs[b] + (t - lstart[b])] = st[t];
    }
}

// ---------------------------------------------------------------------------
// Multisplit p2 (512 thr): one block per bucket; bucket base from in-LDS
// btotal scan; row histogram (first staged pass loads segment into this
// XCD's L2, second pass is L2-hot); place records; emit counts/startArr.
// Scatter stays inside the block's ~8 KB bucket segment (single-XCD safe).
// ---------------------------------------------------------------------------
__global__ __launch_bounds__(512) void k_p2(const int* __restrict__ btotal,
                                            const int2* __restrict__ staged,
                                            int2* __restrict__ edges,
                                            int* __restrict__ counts,
                                            int* __restrict__ startArr) {
    __shared__ int hist[512];
    __shared__ int lstart[512];
    __shared__ int curso[512];
    __shared__ int wsum[8];
    __shared__ int s_base, s_end;
    int k = blockIdx.x;
    int tid = threadIdx.x;
    int rowBase = k << 9;
    int numRows = min(512, N_NODES - rowBase);

    int bt = (tid < NBKT) ? btotal[tid] : 0;
    int bincl = scan_incl<512>(bt, tid, wsum);
    if (tid == k) { s_base = bincl - bt; s_end = bincl; }
    hist[tid] = 0;
    curso[tid] = 0;
    __syncthreads();
    int base = s_base;
    int cnt  = s_end - base;

    for (int t = tid; t < cnt; t += 512)
        atomicAdd(&hist[((unsigned)staged[base + t].x) >> 18], 1);
    __syncthreads();
    int h = hist[tid];
    int hincl = scan_incl<512>(h, tid, wsum);
    lstart[tid] = hincl - h;
    __syncthreads();
    for (int t = tid; t < cnt; t += 512) {
        int2 rec = staged[base + t];
        int rl = ((unsigned)rec.x) >> 18;
        int c  = rec.x & 0x3FFFF;
        int off = lstart[rl] + atomicAdd(&curso[rl], 1);
        edges[base + off] = make_int2(c, rec.y);
    }
    if (tid < numRows) {
        counts[rowBase + tid]   = hist[tid];
        startArr[rowBase + tid] = base + lstart[tid];
    }
}

// ---------------------------------------------------------------------------
// Quad-gather SpMM core (fp8 table).
// 64 lanes = 4 groups of 16; group g handles edges 4q+g. Lane li in a group
// reads one uint (4 fp8 dims) -> 16 lanes cover the 64 B row. ONE vmem
// instruction fetches FOUR edges' rows. At the measured structural floor:
// bf16-wave, bf16-pair, and fp8-quad layouts (2x request, 2.4x byte spread)
// all land at ~42 Gedge/s (~14.5 cy/CU/edge). Do not grow flights.
// ---------------------------------------------------------------------------
template<int P>
__device__ __forceinline__ void qflight(const int2* __restrict__ edges,
                                        const unsigned* __restrict__ tab,
                                        int s, int q, int g, int li,
                                        float& a0, float& a1, float& a2, float& a3) {
    unsigned u[P];
    float    v[P];
    #pragma unroll
    for (int t = 0; t < P; t++) {
        int2 e = edges[s + 4 * (q + t) + g];   // 16 lanes share addr -> 1 line
        v[t] = __int_as_float(e.y);
        u[t] = tab[(size_t)e.x * 16 + li];     // 16 lanes x 4B = full 64B row
    }
    #pragma unroll
    for (int t = 0; t < P; t++) {
        floatx2 lo = __builtin_amdgcn_cvt_pk_f32_fp8(u[t], false);
        floatx2 hi = __builtin_amdgcn_cvt_pk_f32_fp8(u[t], true);
        a0 = fmaf(v[t], lo.x, a0);
        a1 = fmaf(v[t], lo.y, a1);
        a2 = fmaf(v[t], hi.x, a2);
        a3 = fmaf(v[t], hi.y, a3);
    }
}

__device__ __forceinline__ void spmm_row_q(const int2* __restrict__ edges,
                                           const unsigned* __restrict__ tab,
                                           int s, int n, int g, int li,
                                           float& a0, float& a1, float& a2, float& a3) {
    int nq = n >> 2, rem = n & 3;
    int q = 0;
    for (; q + 8 <= nq; q += 8)
        qflight<8>(edges, tab, s, q, g, li, a0, a1, a2, a3);
    if (nq - q >= 4) { qflight<4>(edges, tab, s, q, g, li, a0, a1, a2, a3); q += 4; }
    if (nq - q >= 2) { qflight<2>(edges, tab, s, q, g, li, a0, a1, a2, a3); q += 2; }
    if (nq - q >= 1) { qflight<1>(edges, tab, s, q, g, li, a0, a1, a2, a3); q += 1; }
    if (rem) {                                  // last 1-3 edges, masked
        int gi = (g < rem) ? g : 0;
        int2 e = edges[s + 4 * nq + gi];
        float v = (g < rem) ? __int_as_float(e.y) : 0.f;
        unsigned u = tab[(size_t)e.x * 16 + li];
        floatx2 lo = __builtin_amdgcn_cvt_pk_f32_fp8(u, false);
        floatx2 hi = __builtin_amdgcn_cvt_pk_f32_fp8(u, true);
        a0 = fmaf(v, lo.x, a0);
        a1 = fmaf(v, lo.y, a1);
        a2 = fmaf(v, hi.x, a2);
        a3 = fmaf(v, hi.y, a3);
    }
}

// ---------------------------------------------------------------------------
// Gather SpMM (fp8): one wave per row, quad-gather layout.
// ---------------------------------------------------------------------------
__global__ __launch_bounds__(256) void k_spmm_csr(const int* __restrict__ startArr,
                                                  const int* __restrict__ counts,
                                                  const int2* __restrict__ edges,
                                                  const unsigned* __restrict__ cur,
                                                  unsigned* __restrict__ nxt) {
    int row  = blockIdx.x * 4 + (threadIdx.x >> 6);
    if (row >= N_NODES) return;
    row = __builtin_amdgcn_readfirstlane(row);
    int lane = threadIdx.x & 63;
    int g  = lane >> 4;
    int li = lane & 15;
    int s = __builtin_amdgcn_readfirstlane(startArr[row]);
    int n = __builtin_amdgcn_readfirstlane(counts[row]);

    float a0 = 0.f, a1 = 0.f, a2 = 0.f, a3 = 0.f;
    spmm_row_q(edges, cur, s, n, g, li, a0, a1, a2, a3);

    // combine the 4 edge-groups (butterfly over lane^16, lane^32)
    a0 += __shfl_xor(a0, 16); a0 += __shfl_xor(a0, 32);
    a1 += __shfl_xor(a1, 16); a1 += __shfl_xor(a1, 32);
    a2 += __shfl_xor(a2, 16); a2 += __shfl_xor(a2, 32);
    a3 += __shfl_xor(a3, 16); a3 += __shfl_xor(a3, 32);
    if (g == 0)
        nxt[(size_t)row * 16 + li] = pk4_fp8(a0, a1, a2, a3);
}

// ---------------------------------------------------------------------------
// Fused layer-3 gathers + layer-2 + layer-1 contributions at selected rows.
// SOLE writer of vsel (pure store; layer-0 is added inside k_mlp).
// ---------------------------------------------------------------------------
__global__ __launch_bounds__(256) void k_spmm_sel(const int* __restrict__ users,
                                                  const int* __restrict__ items,
                                                  const int* __restrict__ startArr,
                                                  const int* __restrict__ counts,
                                                  const int2* __restrict__ edges,
                                                  const unsigned* __restrict__ cur,
                                                  const unsigned* __restrict__ lay1,
                                                  float* __restrict__ vsel) {
    int wave = blockIdx.x * 4 + (threadIdx.x >> 6);
    int lane = threadIdx.x & 63;
    int g  = lane >> 4;
    int li = lane & 15;
    int b, row, off;
    if (wave < BATCH) { b = wave;         row = users[b];             off = 0; }
    else              { b = wave - BATCH; row = NUM_USERS + items[b]; off = 64; }
    row = __builtin_amdgcn_readfirstlane(row);
    int s = __builtin_amdgcn_readfirstlane(startArr[row]);
    int n = __builtin_amdgcn_readfirstlane(counts[row]);

    float a0 = 0.f, a1 = 0.f, a2 = 0.f, a3 = 0.f;
    if (g == 0) {                          // layer-2 + layer-1 contributions
        unsigned u2 = cur [(size_t)row * 16 + li];
        unsigned u1 = lay1[(size_t)row * 16 + li];
        floatx2 lo2 = __builtin_amdgcn_cvt_pk_f32_fp8(u2, false);
        floatx2 hi2 = __builtin_amdgcn_cvt_pk_f32_fp8(u2, true);
        floatx2 lo1 = __builtin_amdgcn_cvt_pk_f32_fp8(u1, false);
        floatx2 hi1 = __builtin_amdgcn_cvt_pk_f32_fp8(u1, true);
        a0 = lo2.x + lo1.x; a1 = lo2.y + lo1.y;
        a2 = hi2.x + hi1.x; a3 = hi2.y + hi1.y;
    }
    spmm_row_q(edges, cur, s, n, g, li, a0, a1, a2, a3);

    a0 += __shfl_xor(a0, 16); a0 += __shfl_xor(a0, 32);
    a1 += __shfl_xor(a1, 16); a1 += __shfl_xor(a1, 32);
    a2 += __shfl_xor(a2, 16); a2 += __shfl_xor(a2, 32);
    a3 += __shfl_xor(a3, 16); a3 += __shfl_xor(a3, 32);
    if (g == 0) {
        float4* p = (float4*)(vsel + (size_t)b * 128 + off) + li;
        *p = make_float4(a0, a1, a2, a3);          // pure store, no RMW
    }
}

// ---------------------------------------------------------------------------
// MLP head v5: thread = (row, output-quarter); all register indices static
// (rule #20: runtime-indexed register arrays spill to scratch -- v4 cost
// 65 us / 36 MB writes). W1 panels skewed +8 floats -> banks {0,8,16,24}.
// ---------------------------------------------------------------------------
__global__ __launch_bounds__(256) void k_mlp(const float* __restrict__ vsel,
                                             const int* __restrict__ users,
                                             const int* __restrict__ items,
                                             const float* __restrict__ ue,
                                             const float* __restrict__ ie,
                                             const float* __restrict__ W0,
                                             const float* __restrict__ b0,
                                             const float* __restrict__ W1,
                                             const float* __restrict__ b1,
                                             const float* __restrict__ Wa,
                                             const float* __restrict__ ba,
                                             float* __restrict__ out) {
    __shared__ float sW0[128 * 64];          // row-major, as given
    __shared__ float sW1[4 * 520];           // 4 panels of 16 rows, +8 skew
    __shared__ float sWa[32];
    __shared__ float sb0[64];
    __shared__ float sb1[32];

    for (int i = threadIdx.x; i < 128 * 64; i += 256) sW0[i] = W0[i];
    for (int i = threadIdx.x; i < 64 * 32; i += 256) {
        int k = i >> 5, j = i & 31;
        sW1[(k >> 4) * 520 + (k & 15) * 32 + j] = W1[i];
    }
    if (threadIdx.x < 32) sWa[threadIdx.x] = Wa[threadIdx.x];
    if (threadIdx.x < 64) sb0[threadIdx.x] = b0[threadIdx.x];
    if (threadIdx.x >= 64 && threadIdx.x < 96) sb1[threadIdx.x - 64] = b1[threadIdx.x - 64];
    float sba = ba[0];
    __syncthreads();

    int t = blockIdx.x * 256 + threadIdx.x;
    int b = t >> 2, sub = t & 3;                     // 4 threads per row
    const float4* v4  = (const float4*)(vsel + (size_t)b * 128);
    const float4* ue4 = (const float4*)(ue + (size_t)users[b] * 64);
    const float4* ie4 = (const float4*)(ie + (size_t)items[b] * 64);

    // h0s[j] = thread's 16 neurons (cols sub*16 .. +15), bias-initialized
    float h0s[16];
    {
        const float4* bb = (const float4*)&sb0[sub * 16];
        #pragma unroll
        for (int q = 0; q < 4; q++) {
            float4 bv = bb[q];
            h0s[q * 4 + 0] = bv.x; h0s[q * 4 + 1] = bv.y;
            h0s[q * 4 + 2] = bv.z; h0s[q * 4 + 3] = bv.w;
        }
    }

    #pragma unroll
    for (int k0 = 0; k0 < 32; k0++) {                // 4 inputs per iter
        float4 va = v4[k0];
        float4 ea = (k0 < 16) ? ue4[k0] : ie4[k0 - 16];
        float a[4] = { (va.x + ea.x) * 0.25f, (va.y + ea.y) * 0.25f,
                       (va.z + ea.z) * 0.25f, (va.w + ea.w) * 0.25f };
        #pragma unroll
        for (int r = 0; r < 4; r++) {
            const float4* w4 = (const float4*)&sW0[(k0 * 4 + r) * 64 + sub * 16];
            float ar = a[r];
            #pragma unroll
            for (int q = 0; q < 4; q++) {
                float4 wv = w4[q];
                h0s[q * 4 + 0] = fmaf(ar, wv.x, h0s[q * 4 + 0]);
                h0s[q * 4 + 1] = fmaf(ar, wv.y, h0s[q * 4 + 1]);
                h0s[q * 4 + 2] = fmaf(ar, wv.z, h0s[q * 4 + 2]);
                h0s[q * 4 + 3] = fmaf(ar, wv.w, h0s[q * 4 + 3]);
            }
        }
    }
    #pragma unroll
    for (int j = 0; j < 16; j++) h0s[j] = fmaxf(h0s[j], 0.f);

    // h1 partials from this thread's 16 h0 rows (W1 rows sub*16..+15)
    float h1p[32];
    #pragma unroll
    for (int j = 0; j < 32; j++) h1p[j] = 0.f;
    #pragma unroll
    for (int kk = 0; kk < 16; kk++) {
        float a = h0s[kk];
        const float4* w4 = (const float4*)&sW1[sub * 520 + kk * 32];
        #pragma unroll
        for (int q = 0; q < 8; q++) {
            float4 wv = w4[q];
            h1p[q * 4 + 0] = fmaf(a, wv.x, h1p[q * 4 + 0]);
            h1p[q * 4 + 1] = fmaf(a, wv.y, h1p[q * 4 + 1]);
            h1p[q * 4 + 2] = fmaf(a, wv.z, h1p[q * 4 + 2]);
            h1p[q * 4 + 3] = fmaf(a, wv.w, h1p[q * 4 + 3]);
        }
    }
    // reduce partials across the 4 subs (quad stays inside the wave)
    #pragma unroll
    for (int j = 0; j < 32; j++) {
        h1p[j] += __shfl_xor(h1p[j], 1);
        h1p[j] += __shfl_xor(h1p[j], 2);
    }

    float logit = sba;
    #pragma unroll
    for (int j = 0; j < 32; j++)
        logit = fmaf(fmaxf(h1p[j] + sb1[j], 0.f), sWa[j], logit);

    if (sub == 0) out[b] = 1.0f / (1.0f + expf(-logit));
}

// ---------------------------------------------------------------------------
extern "C" void kernel_launch(void* const* d_in, const int* in_sizes, int n_in,
                              void* d_out, int out_size, void* d_ws, size_t ws_size,
                              hipStream_t stream) {
    const int*   users = (const int*)  d_in[0];
    const int*   items = (const int*)  d_in[1];
    const int*   rows  = (const int*)  d_in[2];
    const int*   cols  = (const int*)  d_in[3];
    const float* vals  = (const float*)d_in[4];
    const float* ue    = (const float*)d_in[5];
    const float* ie    = (const float*)d_in[6];
    const float* W0    = (const float*)d_in[7];
    const float* b0    = (const float*)d_in[8];
    const float* W1    = (const float*)d_in[9];
    const float* b1    = (const float*)d_in[10];
    const float* Wa    = (const float*)d_in[11];
    const float* ba    = (const float*)d_in[12];
    float* out = (float*)d_out;

    char* ws = (char*)d_ws;
    unsigned* tabA8 = (unsigned*)ws;  ws += (size_t)N_NODES * 64;                // 9.6 MB
    unsigned* tabB8 = (unsigned*)ws;  ws += (size_t)N_NODES * 64;                // 9.6 MB
    float* vsel = (float*)ws;         ws += (size_t)BATCH * 128 * 4;             // 8.39 MB
    int2*  edges  = (int2*)ws;        ws += (size_t)N_EDGES * 8;                 // 19.2 MB
    int2*  staged = (int2*)ws;        ws += (size_t)N_EDGES * 8;                 // 19.2 MB
    int* counts   = (int*)ws;         ws += N_NODES * 4;
    int* startArr = (int*)ws;         ws += N_NODES * 4;
    int* cmat     = (int*)ws;         ws += (size_t)NBKT * NBLK * 4;             // 686 KB
    int* bcnt     = (int*)ws;         ws += (size_t)NBKT * NBLK * 4;             // 686 KB
    int* btotal   = (int*)ws;         ws += NBKT * 4;

    // fp8 table + p1a histogram (fused, one dispatch)
    k_prep<<<NBLK + CONCAT_BLKS, 256, 0, stream>>>(
        (const float4*)ue, (const float4*)ie, tabA8, rows, cmat);

    // ---- CSR build: zero global atomics, no bscan dispatch ----
    k_p1b<<<NBKT, 1024, 0, stream>>>(cmat, bcnt, btotal);
    k_p1c<<<NBLK, 512, 0, stream>>>(rows, cols, vals, cmat, bcnt, btotal, staged);
    k_p2<<<NBKT, 512, 0, stream>>>(btotal, staged, edges, counts, startArr);

    // layer 1: A -> B (writes every row; no memset needed)
    k_spmm_csr<<<(N_NODES + 3) / 4, 256, 0, stream>>>(startArr, counts, edges, tabA8, tabB8);

    // layer 2: B -> A  (tabB8 stays intact for the fused sel below)
    k_spmm_csr<<<(N_NODES + 3) / 4, 256, 0, stream>>>(startArr, counts, edges, tabB8, tabA8);

    // layer 3 gathers + layer-2 + layer-1 adds at selected rows (fused);
    // sole writer of vsel
    k_spmm_sel<<<(2 * BATCH) / 4, 256, 0, stream>>>(users, items, startArr,
                                                    counts, edges, tabA8, tabB8, vsel);

    // MLP head: 4 threads per row, layer-0 gather fused, no scratch
    k_mlp<<<(BATCH * 4) / 256, 256, 0, stream>>>(vsel, users, items, ue, ie,
                                                 W0, b0, W1, b1, Wa, ba, out);
}